// Round 12
// baseline (466.369 us; speedup 1.0000x reference)
//
#include <hip/hip_runtime.h>
#include <cstdint>
#include <cstddef>

typedef _Float16 half8 __attribute__((ext_vector_type(8)));
typedef _Float16 half4 __attribute__((ext_vector_type(4)));
typedef __fp16 fp16x2 __attribute__((ext_vector_type(2)));
typedef float f32x4 __attribute__((ext_vector_type(4)));
typedef int int2v __attribute__((ext_vector_type(2)));

#define MFMA16(a, b, c) __builtin_amdgcn_mfma_f32_16x16x32_f16((a), (b), (c), 0, 0, 0)
#define MFMA16x16(a, b, c) __builtin_amdgcn_mfma_f32_16x16x16f16((a), (b), (c), 0, 0, 0)

__device__ __forceinline__ void gload_lds16(const void* g, void* l) {
  __builtin_amdgcn_global_load_lds(
      (const __attribute__((address_space(1))) void*)g,
      (__attribute__((address_space(3))) void*)l, 16, 0, 0);
}

__device__ __forceinline__ float fexp2(float x) {
#if __has_builtin(__builtin_amdgcn_exp2f)
  return __builtin_amdgcn_exp2f(x);
#else
  return exp2f(x);
#endif
}

__device__ __forceinline__ int cvtpk16(float a, float b) {
  fp16x2 h = __builtin_amdgcn_cvt_pkrtz(a, b);
  return __builtin_bit_cast(int, h);
}

// ---------------------------------------------------------------------------
// fp32 -> f16 convert: query/key/value (8.4M each) + Wq/Wk/Wv (1M each)
// ---------------------------------------------------------------------------
__global__ __launch_bounds__(256) void cvt_f16(
    const float* __restrict__ q, const float* __restrict__ k, const float* __restrict__ v,
    const float* __restrict__ wq, const float* __restrict__ wk, const float* __restrict__ wv,
    _Float16* __restrict__ xq, _Float16* __restrict__ xk, _Float16* __restrict__ xv,
    _Float16* __restrict__ wq16, _Float16* __restrict__ wk16, _Float16* __restrict__ wv16)
{
  constexpr int S8 = 1048576;  // 8.4M/8
  constexpr int W8 = 131072;   // 1M/8
  int u = blockIdx.x * 256 + threadIdx.x;
  const float* src;
  _Float16* dst;
  if (u < S8) { src = q; dst = xq; }
  else if ((u -= S8) < S8) { src = k; dst = xk; }
  else if ((u -= S8) < S8) { src = v; dst = xv; }
  else if ((u -= S8) < W8) { src = wq; dst = wq16; }
  else if ((u -= W8) < W8) { src = wk; dst = wk16; }
  else { u -= W8; src = wv; dst = wv16; }
  const float4 f0 = reinterpret_cast<const float4*>(src)[u * 2];
  const float4 f1 = reinterpret_cast<const float4*>(src)[u * 2 + 1];
  half8 h;
  h[0] = (_Float16)f0.x; h[1] = (_Float16)f0.y; h[2] = (_Float16)f0.z; h[3] = (_Float16)f0.w;
  h[4] = (_Float16)f1.x; h[5] = (_Float16)f1.y; h[6] = (_Float16)f1.z; h[7] = (_Float16)f1.w;
  reinterpret_cast<half8*>(dst)[u] = h;
}

// ---------------------------------------------------------------------------
// V transpose: v[g][k][d] -> vt[g][d][k]  (g=64, k=2048, d=64), LDS 64x64 tile
// ---------------------------------------------------------------------------
__global__ __launch_bounds__(256) void vtrans(
    const _Float16* __restrict__ v, _Float16* __restrict__ vt)
{
  __shared__ _Float16 T[64][72];
  const int g = blockIdx.y, kt = blockIdx.x;
  const int tid = threadIdx.x;
  const size_t gbase = (size_t)g * 131072;
  const int sr = tid >> 2, sc = (tid & 3) * 16;
  {
    const half8* src = reinterpret_cast<const half8*>(v + gbase + (size_t)(kt * 64 + sr) * 64 + sc);
    *reinterpret_cast<half8*>(&T[sr][sc]) = src[0];
    *reinterpret_cast<half8*>(&T[sr][sc + 8]) = src[1];
  }
  __syncthreads();
  const int d = tid >> 2, kc = (tid & 3) * 16;
  half8 h0, h1;
#pragma unroll
  for (int j = 0; j < 8; ++j) { h0[j] = T[kc + j][d]; h1[j] = T[kc + 8 + j][d]; }
  half8* dst = reinterpret_cast<half8*>(vt + gbase + (size_t)d * 2048 + kt * 64 + kc);
  dst[0] = h0;
  dst[1] = h1;
}

// ---------------------------------------------------------------------------
// m97-style GEMM: Out[M,N] = A[M,K] @ W[N,K]^T + bias (+resid)
// ---------------------------------------------------------------------------
template <bool WF32, bool RES>
__global__ __launch_bounds__(256) void gemm128(
    const _Float16* __restrict__ A, const void* __restrict__ Wp,
    const float* __restrict__ bias, const float* __restrict__ resid,
    void* __restrict__ Out, int N, float scale)
{
  constexpr int K = 1024;
  __shared__ _Float16 As[128 * 64];
  __shared__ _Float16 Bs[128 * 64];
  const int tid = threadIdx.x;
  const int lane = tid & 63, w = tid >> 6;
  const int lo = lane & 15, hi = lane >> 4;
  const int wr = w >> 1, wc = w & 1;
  const int rbase = blockIdx.x * 128, cbase = blockIdx.y * 128;
  const int e0 = w * 512 + lane * 8;

  f32x4 acc[4][4];
#pragma unroll
  for (int m = 0; m < 4; ++m)
#pragma unroll
    for (int n = 0; n < 4; ++n) acc[m][n] = f32x4{0.f, 0.f, 0.f, 0.f};

  for (int kk = 0; kk < K; kk += 64) {
    __syncthreads();
#pragma unroll
    for (int i = 0; i < 4; ++i) {
      const int e = i * 2048 + e0;
      gload_lds16(A + (size_t)(rbase + (e >> 6)) * K + kk + (e & 63),
                  (char*)As + i * 4096 + w * 1024);
    }
    if constexpr (!WF32) {
#pragma unroll
      for (int i = 0; i < 4; ++i) {
        const int e = i * 2048 + e0;
        gload_lds16((const _Float16*)Wp + (size_t)(cbase + (e >> 6)) * K + kk + (e & 63),
                    (char*)Bs + i * 4096 + w * 1024);
      }
    } else {
#pragma unroll
      for (int i = 0; i < 4; ++i) {
        const int e = i * 2048 + e0;
        const float4* src = reinterpret_cast<const float4*>(
            (const float*)Wp + (size_t)(cbase + (e >> 6)) * K + kk + (e & 63));
        const float4 f0 = src[0], f1 = src[1];
        half8 h;
        h[0] = (_Float16)f0.x; h[1] = (_Float16)f0.y; h[2] = (_Float16)f0.z; h[3] = (_Float16)f0.w;
        h[4] = (_Float16)f1.x; h[5] = (_Float16)f1.y; h[6] = (_Float16)f1.z; h[7] = (_Float16)f1.w;
        *reinterpret_cast<half8*>(Bs + e) = h;
      }
    }
    __syncthreads();
#pragma unroll
    for (int k0 = 0; k0 < 2; ++k0) {
      half8 a[4], b[4];
#pragma unroll
      for (int m = 0; m < 4; ++m)
        a[m] = *reinterpret_cast<const half8*>(As + (wr * 64 + m * 16 + lo) * 64 + k0 * 32 + hi * 8);
#pragma unroll
      for (int n = 0; n < 4; ++n)
        b[n] = *reinterpret_cast<const half8*>(Bs + (wc * 64 + n * 16 + lo) * 64 + k0 * 32 + hi * 8);
#pragma unroll
      for (int m = 0; m < 4; ++m)
#pragma unroll
        for (int n = 0; n < 4; ++n) acc[m][n] = MFMA16(a[m], b[n], acc[m][n]);
    }
  }
#pragma unroll
  for (int m = 0; m < 4; ++m) {
#pragma unroll
    for (int n = 0; n < 4; ++n) {
      const int col = cbase + wc * 64 + n * 16 + lo;
      const float bv = bias[col];
#pragma unroll
      for (int r = 0; r < 4; ++r) {
        const int row = rbase + wr * 64 + m * 16 + hi * 4 + r;
        float v = acc[m][n][r] + bv;
        if constexpr (RES) {
          v += resid[(size_t)row * 1024 + col];
          ((float*)Out)[(size_t)row * N + col] = v;
        } else {
          ((_Float16*)Out)[(size_t)row * N + col] = (_Float16)(v * scale);
        }
      }
    }
  }
}

// ---------------------------------------------------------------------------
// Fused attention, 3-phase pipelined two-tile schedule (8 waves, 512 thr).
// Block owns two 128-row q-tiles A,B of group g:
//   phase A: pass-1(A)                       [no stores - short dark window]
//   phase B: pass-2(A) + pass-1(B) fused     [stores flow, shared K staging]
//   phase C: pass-2(B)                       [stores flow]
// Each wave: 16 q-rows per tile (row = qt + w*16 + lo), swapped-operand QK^T
// (lane-local P), -dr in accumulator, cvt_pk PV fragments, LDS-formatted
// full-line nontemporal P stores (R9/R11-validated).
// LDS = 64 KB -> 2 blocks/CU (16 waves/CU).
// ---------------------------------------------------------------------------
__global__ __launch_bounds__(512) void attn_fused(
    const _Float16* __restrict__ qg, const _Float16* __restrict__ kg,
    const _Float16* __restrict__ vtg, _Float16* __restrict__ ctx,
    float* __restrict__ attnp)
{
  __shared__ _Float16 Kt[2][64 * 64];
  __shared__ _Float16 Vt[2][64 * 64];
  __shared__ float Ps[8 * 1024];  // per-wave 16 rows x 64 f32
  const int tid = threadIdx.x;
  const int lane = tid & 63, w = tid >> 6;
  const int lo = lane & 15, hi = lane >> 4;
  const int bid = blockIdx.x;
  const int g = bid & 63;
  const int qA = (bid >> 6) * 256;
  const int qB = qA + 128;
  const size_t gbase = (size_t)g * (2048 * 64);
  const int e0 = tid * 8;  // 512 thr x 8 elem = one 64x64 f16 tile
  const int r0 = e0 >> 6, c0 = (e0 & 63) ^ ((r0 & 7) << 3);

  float* ab = attnp + (size_t)g * 2048 * 2048;
  const _Float16* vtb = vtg + (size_t)g * (64 * 2048);
  float* Pw = Ps + w * 1024;

  // Q fragments for both tiles (registers, all phases)
  half8 qf[2][2];
#pragma unroll
  for (int t = 0; t < 2; ++t)
#pragma unroll
    for (int k0 = 0; k0 < 2; ++k0)
      qf[t][k0] = *reinterpret_cast<const half8*>(
          qg + gbase + (size_t)((t ? qB : qA) + w * 16 + lo) * 64 + k0 * 32 + hi * 8);

  // ================= phase A: pass-1(tile A) =================
  float lsA = 0.f;
  gload_lds16(kg + gbase + (size_t)r0 * 64 + c0, (char*)Kt[0] + w * 1024);
  for (int kt = 0; kt < 32; ++kt) {
    const int cur = kt & 1;
    __syncthreads();
    if (kt < 31) {
      gload_lds16(kg + gbase + (size_t)(kt + 1) * 4096 + (size_t)r0 * 64 + c0,
                  (char*)Kt[cur ^ 1] + w * 1024);
    }
    f32x4 s[4];
#pragma unroll
    for (int n = 0; n < 4; ++n) s[n] = f32x4{0.f, 0.f, 0.f, 0.f};
#pragma unroll
    for (int k0 = 0; k0 < 2; ++k0) {
      half8 b[4];
#pragma unroll
      for (int n = 0; n < 4; ++n) {
        const int row = n * 16 + lo;
        b[n] = *reinterpret_cast<const half8*>(
            Kt[cur] + row * 64 + ((k0 * 32 + hi * 8) ^ ((row & 7) << 3)));
      }
#pragma unroll
      for (int n = 0; n < 4; ++n) s[n] = MFMA16(b[n], qf[0][k0], s[n]);
    }
    float t = 0.f;
#pragma unroll
    for (int nb = 0; nb < 4; ++nb)
#pragma unroll
      for (int r = 0; r < 4; ++r) t += fexp2(s[nb][r]);
    lsA += t;
  }
  float drA;
  {
    float t = lsA;
    t += __shfl_xor(t, 16, 64);
    t += __shfl_xor(t, 32, 64);
    drA = __log2f(t);
  }

  // ================= phase B: pass-2(A) + pass-1(B) =================
  float lsB = 0.f;
  f32x4 o[4];
#pragma unroll
  for (int n = 0; n < 4; ++n) o[n] = f32x4{0.f, 0.f, 0.f, 0.f};
  gload_lds16(kg + gbase + (size_t)r0 * 64 + c0, (char*)Kt[0] + w * 1024);
  gload_lds16(vtb + (size_t)r0 * 2048 + c0, (char*)Vt[0] + w * 1024);

  for (int kt = 0; kt < 32; ++kt) {
    const int cur = kt & 1;
    if (kt == 0) asm volatile("s_waitcnt vmcnt(0) lgkmcnt(0)" ::: "memory");
    else asm volatile("s_waitcnt vmcnt(4) lgkmcnt(0)" ::: "memory");
    __builtin_amdgcn_s_barrier();
    __builtin_amdgcn_sched_barrier(0);
    if (kt < 31) {
      gload_lds16(kg + gbase + (size_t)(kt + 1) * 4096 + (size_t)r0 * 64 + c0,
                  (char*)Kt[cur ^ 1] + w * 1024);
      gload_lds16(vtb + (kt + 1) * 64 + (size_t)r0 * 2048 + c0,
                  (char*)Vt[cur ^ 1] + w * 1024);
    }
    __builtin_amdgcn_sched_barrier(0);
    f32x4 sA[4], sB[4];
#pragma unroll
    for (int n = 0; n < 4; ++n) {
      sA[n] = f32x4{-drA, -drA, -drA, -drA};
      sB[n] = f32x4{0.f, 0.f, 0.f, 0.f};
    }
#pragma unroll
    for (int k0 = 0; k0 < 2; ++k0) {
      half8 b[4];
#pragma unroll
      for (int n = 0; n < 4; ++n) {
        const int row = n * 16 + lo;
        b[n] = *reinterpret_cast<const half8*>(
            Kt[cur] + row * 64 + ((k0 * 32 + hi * 8) ^ ((row & 7) << 3)));
      }
#pragma unroll
      for (int n = 0; n < 4; ++n) {
        sA[n] = MFMA16(b[n], qf[0][k0], sA[n]);
        sB[n] = MFMA16(b[n], qf[1][k0], sB[n]);
      }
    }
    // P(A): exp -> pk regs + LDS format + full-line nt stores
    int pk[4][2];
#pragma unroll
    for (int nb = 0; nb < 4; ++nb) {
      const float p0 = fexp2(sA[nb][0]);
      const float p1 = fexp2(sA[nb][1]);
      const float p2 = fexp2(sA[nb][2]);
      const float p3 = fexp2(sA[nb][3]);
      pk[nb][0] = cvtpk16(p0, p1);
      pk[nb][1] = cvtpk16(p2, p3);
      const f32x4 f = {p0, p1, p2, p3};
      *reinterpret_cast<f32x4*>(Pw + lo * 64 + ((nb * 16 + hi * 4) ^ (lo << 2))) = f;
    }
    asm volatile("s_waitcnt lgkmcnt(0)" ::: "memory");
#pragma unroll
    for (int i = 0; i < 4; ++i) {
      const int rl = i * 4 + (lane >> 4);
      const int klo = (lane & 15) * 4;
      const f32x4 f = *reinterpret_cast<const f32x4*>(Pw + rl * 64 + (klo ^ (rl << 2)));
      __builtin_nontemporal_store(
          f, reinterpret_cast<f32x4*>(
                 ab + (size_t)(qA + w * 16 + rl) * 2048 + kt * 64 + klo));
    }
    asm volatile("s_waitcnt lgkmcnt(0)" ::: "memory");  // WAR before next-iter Ps write
    // pass-1(B) accumulate
    {
      float t = 0.f;
#pragma unroll
      for (int nb = 0; nb < 4; ++nb)
#pragma unroll
        for (int r = 0; r < 4; ++r) t += fexp2(sB[nb][r]);
      lsB += t;
    }
    // PV(A)
#pragma unroll
    for (int nb = 0; nb < 4; ++nb) {
      half4 vb[4];
#pragma unroll
      for (int n = 0; n < 4; ++n) {
        const int d = n * 16 + lo;
        vb[n] = *reinterpret_cast<const half4*>(
            Vt[cur] + d * 64 + ((nb * 16 + hi * 4) ^ ((d & 7) << 3)));
      }
      const int2v t2 = {pk[nb][0], pk[nb][1]};
      const half4 pa = __builtin_bit_cast(half4, t2);
#pragma unroll
      for (int n = 0; n < 4; ++n) o[n] = MFMA16x16(pa, vb[n], o[n]);
    }
  }
  // ctx(A)
#pragma unroll
  for (int n = 0; n < 4; ++n)
#pragma unroll
    for (int r = 0; r < 4; ++r)
      ctx[gbase + (size_t)(qA + w * 16 + hi * 4 + r) * 64 + n * 16 + lo] =
          (_Float16)o[n][r];
  float drB;
  {
    float t = lsB;
    t += __shfl_xor(t, 16, 64);
    t += __shfl_xor(t, 32, 64);
    drB = __log2f(t);
  }

  // ================= phase C: pass-2(B) =================
#pragma unroll
  for (int n = 0; n < 4; ++n) o[n] = f32x4{0.f, 0.f, 0.f, 0.f};
  gload_lds16(kg + gbase + (size_t)r0 * 64 + c0, (char*)Kt[0] + w * 1024);
  gload_lds16(vtb + (size_t)r0 * 2048 + c0, (char*)Vt[0] + w * 1024);

  for (int kt = 0; kt < 32; ++kt) {
    const int cur = kt & 1;
    if (kt == 0) asm volatile("s_waitcnt vmcnt(0) lgkmcnt(0)" ::: "memory");
    else asm volatile("s_waitcnt vmcnt(4) lgkmcnt(0)" ::: "memory");
    __builtin_amdgcn_s_barrier();
    __builtin_amdgcn_sched_barrier(0);
    if (kt < 31) {
      gload_lds16(kg + gbase + (size_t)(kt + 1) * 4096 + (size_t)r0 * 64 + c0,
                  (char*)Kt[cur ^ 1] + w * 1024);
      gload_lds16(vtb + (kt + 1) * 64 + (size_t)r0 * 2048 + c0,
                  (char*)Vt[cur ^ 1] + w * 1024);
    }
    __builtin_amdgcn_sched_barrier(0);
    f32x4 s[4];
#pragma unroll
    for (int n = 0; n < 4; ++n) s[n] = f32x4{-drB, -drB, -drB, -drB};
#pragma unroll
    for (int k0 = 0; k0 < 2; ++k0) {
      half8 b[4];
#pragma unroll
      for (int n = 0; n < 4; ++n) {
        const int row = n * 16 + lo;
        b[n] = *reinterpret_cast<const half8*>(
            Kt[cur] + row * 64 + ((k0 * 32 + hi * 8) ^ ((row & 7) << 3)));
      }
#pragma unroll
      for (int n = 0; n < 4; ++n) s[n] = MFMA16(b[n], qf[1][k0], s[n]);
    }
    int pk[4][2];
#pragma unroll
    for (int nb = 0; nb < 4; ++nb) {
      const float p0 = fexp2(s[nb][0]);
      const float p1 = fexp2(s[nb][1]);
      const float p2 = fexp2(s[nb][2]);
      const float p3 = fexp2(s[nb][3]);
      pk[nb][0] = cvtpk16(p0, p1);
      pk[nb][1] = cvtpk16(p2, p3);
      const f32x4 f = {p0, p1, p2, p3};
      *reinterpret_cast<f32x4*>(Pw + lo * 64 + ((nb * 16 + hi * 4) ^ (lo << 2))) = f;
    }
    asm volatile("s_waitcnt lgkmcnt(0)" ::: "memory");
#pragma unroll
    for (int i = 0; i < 4; ++i) {
      const int rl = i * 4 + (lane >> 4);
      const int klo = (lane & 15) * 4;
      const f32x4 f = *reinterpret_cast<const f32x4*>(Pw + rl * 64 + (klo ^ (rl << 2)));
      __builtin_nontemporal_store(
          f, reinterpret_cast<f32x4*>(
                 ab + (size_t)(qB + w * 16 + rl) * 2048 + kt * 64 + klo));
    }
    asm volatile("s_waitcnt lgkmcnt(0)" ::: "memory");
#pragma unroll
    for (int nb = 0; nb < 4; ++nb) {
      half4 vb[4];
#pragma unroll
      for (int n = 0; n < 4; ++n) {
        const int d = n * 16 + lo;
        vb[n] = *reinterpret_cast<const half4*>(
            Vt[cur] + d * 64 + ((nb * 16 + hi * 4) ^ ((d & 7) << 3)));
      }
      const int2v t2 = {pk[nb][0], pk[nb][1]};
      const half4 pa = __builtin_bit_cast(half4, t2);
#pragma unroll
      for (int n = 0; n < 4; ++n) o[n] = MFMA16x16(pa, vb[n], o[n]);
    }
  }
#pragma unroll
  for (int n = 0; n < 4; ++n)
#pragma unroll
    for (int r = 0; r < 4; ++r)
      ctx[gbase + (size_t)(qB + w * 16 + hi * 4 + r) * 64 + n * 16 + lo] =
          (_Float16)o[n][r];
}

// ---------------------------------------------------------------------------
// In-place LayerNorm over rows of x[8192][1024]
// ---------------------------------------------------------------------------
__global__ __launch_bounds__(256) void ln_kernel(
    float* __restrict__ x, const float* __restrict__ gamma, const float* __restrict__ beta)
{
  const int row = blockIdx.x;
  const int t = threadIdx.x;
  float4 v = *reinterpret_cast<float4*>(x + (size_t)row * 1024 + t * 4);
  float s = v.x + v.y + v.z + v.w;
  float ss = v.x * v.x + v.y * v.y + v.z * v.z + v.w * v.w;
#pragma unroll
  for (int off = 1; off < 64; off <<= 1) {
    s += __shfl_xor(s, off, 64);
    ss += __shfl_xor(ss, off, 64);
  }
  __shared__ float sm[8];
  const int wv = t >> 6, ln = t & 63;
  if (ln == 0) { sm[wv] = s; sm[4 + wv] = ss; }
  __syncthreads();
  s = sm[0] + sm[1] + sm[2] + sm[3];
  ss = sm[4] + sm[5] + sm[6] + sm[7];
  const float mu = s * (1.0f / 1024.0f);
  const float var = ss * (1.0f / 1024.0f) - mu * mu;
  const float rstd = rsqrtf(var + 1e-5f);
  const float4 gv = *reinterpret_cast<const float4*>(gamma + t * 4);
  const float4 bv = *reinterpret_cast<const float4*>(beta + t * 4);
  v.x = (v.x - mu) * rstd * gv.x + bv.x;
  v.y = (v.y - mu) * rstd * gv.y + bv.y;
  v.z = (v.z - mu) * rstd * gv.z + bv.z;
  v.w = (v.w - mu) * rstd * gv.w + bv.w;
  *reinterpret_cast<float4*>(x + (size_t)row * 1024 + t * 4) = v;
}

// ---------------------------------------------------------------------------
extern "C" void kernel_launch(void* const* d_in, const int* in_sizes, int n_in,
                              void* d_out, int out_size, void* d_ws, size_t ws_size,
                              hipStream_t stream) {
  const float* query = (const float*)d_in[0];
  const float* key_ = (const float*)d_in[1];
  const float* value = (const float*)d_in[2];
  const float* Wq = (const float*)d_in[3];
  const float* bq = (const float*)d_in[4];
  const float* Wk = (const float*)d_in[5];
  const float* bk = (const float*)d_in[6];
  const float* Wv = (const float*)d_in[7];
  const float* bv = (const float*)d_in[8];
  const float* Wo = (const float*)d_in[9];
  const float* bo = (const float*)d_in[10];
  const float* gamma = (const float*)d_in[11];
  const float* beta = (const float*)d_in[12];

  float* out = (float*)d_out;
  float* attnp = out + (size_t)8192 * 1024;

  // f16 conversion scratch in the not-yet-written attention output region.
  _Float16* xq = (_Float16*)attnp;
  _Float16* xk = xq + (size_t)8388608;
  _Float16* xv = xk + (size_t)8388608;
  _Float16* wq16 = xv + (size_t)8388608;
  _Float16* wk16 = wq16 + (size_t)1048576;
  _Float16* wv16 = wk16 + (size_t)1048576;

  // vt (16.8 MB) in out[0:16.8MB] — dead until out-proj.
  _Float16* vt = (_Float16*)out;

  _Float16* qb = (_Float16*)d_ws;
  _Float16* kb2 = qb + (size_t)8388608;
  _Float16* vb2 = kb2 + (size_t)8388608;
  _Float16* ctx = vb2;  // vb2 free after vtrans

  constexpr float QSCALE = 0.125f * 1.44269504088896f;

  cvt_f16<<<dim3(13824), dim3(256), 0, stream>>>(query, key_, value, Wq, Wk, Wv,
                                                 xq, xk, xv, wq16, wk16, wv16);
  gemm128<false, false><<<dim3(64, 8), dim3(256), 0, stream>>>(xq, wq16, bq, nullptr, qb, 1024, QSCALE);
  gemm128<false, false><<<dim3(64, 8), dim3(256), 0, stream>>>(xk, wk16, bk, nullptr, kb2, 1024, 1.0f);
  gemm128<false, false><<<dim3(64, 8), dim3(256), 0, stream>>>(xv, wv16, bv, nullptr, vb2, 1024, 1.0f);
  vtrans<<<dim3(32, 64), dim3(256), 0, stream>>>(vb2, vt);
  attn_fused<<<dim3(512), dim3(512), 0, stream>>>(qb, kb2, vt, ctx, attnp);
  gemm128<true, true><<<dim3(64, 8), dim3(256), 0, stream>>>(ctx, Wo, bo, query, out, 1024, 1.0f);
  ln_kernel<<<dim3(8192), dim3(256), 0, stream>>>(out, gamma, beta);
}

// Round 13
// 454.593 us; speedup vs baseline: 1.0259x; 1.0259x over previous
//
#include <hip/hip_runtime.h>
#include <cstdint>
#include <cstddef>

typedef _Float16 half8 __attribute__((ext_vector_type(8)));
typedef _Float16 half4 __attribute__((ext_vector_type(4)));
typedef __fp16 fp16x2 __attribute__((ext_vector_type(2)));
typedef float f32x4 __attribute__((ext_vector_type(4)));
typedef int int2v __attribute__((ext_vector_type(2)));

#define MFMA16(a, b, c) __builtin_amdgcn_mfma_f32_16x16x32_f16((a), (b), (c), 0, 0, 0)
#define MFMA16x16(a, b, c) __builtin_amdgcn_mfma_f32_16x16x16f16((a), (b), (c), 0, 0, 0)

__device__ __forceinline__ void gload_lds16(const void* g, void* l) {
  __builtin_amdgcn_global_load_lds(
      (const __attribute__((address_space(1))) void*)g,
      (__attribute__((address_space(3))) void*)l, 16, 0, 0);
}

__device__ __forceinline__ float fexp2(float x) {
#if __has_builtin(__builtin_amdgcn_exp2f)
  return __builtin_amdgcn_exp2f(x);
#else
  return exp2f(x);
#endif
}

__device__ __forceinline__ int cvtpk16(float a, float b) {
  fp16x2 h = __builtin_amdgcn_cvt_pkrtz(a, b);
  return __builtin_bit_cast(int, h);
}

// ---------------------------------------------------------------------------
// fp32 -> f16 convert: query/key/value (8.4M each) + Wq/Wk/Wv (1M each)
// ---------------------------------------------------------------------------
__global__ __launch_bounds__(256) void cvt_f16(
    const float* __restrict__ q, const float* __restrict__ k, const float* __restrict__ v,
    const float* __restrict__ wq, const float* __restrict__ wk, const float* __restrict__ wv,
    _Float16* __restrict__ xq, _Float16* __restrict__ xk, _Float16* __restrict__ xv,
    _Float16* __restrict__ wq16, _Float16* __restrict__ wk16, _Float16* __restrict__ wv16)
{
  constexpr int S8 = 1048576;  // 8.4M/8
  constexpr int W8 = 131072;   // 1M/8
  int u = blockIdx.x * 256 + threadIdx.x;
  const float* src;
  _Float16* dst;
  if (u < S8) { src = q; dst = xq; }
  else if ((u -= S8) < S8) { src = k; dst = xk; }
  else if ((u -= S8) < S8) { src = v; dst = xv; }
  else if ((u -= S8) < W8) { src = wq; dst = wq16; }
  else if ((u -= W8) < W8) { src = wk; dst = wk16; }
  else { u -= W8; src = wv; dst = wv16; }
  const float4 f0 = reinterpret_cast<const float4*>(src)[u * 2];
  const float4 f1 = reinterpret_cast<const float4*>(src)[u * 2 + 1];
  half8 h;
  h[0] = (_Float16)f0.x; h[1] = (_Float16)f0.y; h[2] = (_Float16)f0.z; h[3] = (_Float16)f0.w;
  h[4] = (_Float16)f1.x; h[5] = (_Float16)f1.y; h[6] = (_Float16)f1.z; h[7] = (_Float16)f1.w;
  reinterpret_cast<half8*>(dst)[u] = h;
}

// ---------------------------------------------------------------------------
// V transpose: v[g][k][d] -> vt[g][d][k]  (g=64, k=2048, d=64), LDS 64x64 tile
// ---------------------------------------------------------------------------
__global__ __launch_bounds__(256) void vtrans(
    const _Float16* __restrict__ v, _Float16* __restrict__ vt)
{
  __shared__ _Float16 T[64][72];
  const int g = blockIdx.y, kt = blockIdx.x;
  const int tid = threadIdx.x;
  const size_t gbase = (size_t)g * 131072;
  const int sr = tid >> 2, sc = (tid & 3) * 16;
  {
    const half8* src = reinterpret_cast<const half8*>(v + gbase + (size_t)(kt * 64 + sr) * 64 + sc);
    *reinterpret_cast<half8*>(&T[sr][sc]) = src[0];
    *reinterpret_cast<half8*>(&T[sr][sc + 8]) = src[1];
  }
  __syncthreads();
  const int d = tid >> 2, kc = (tid & 3) * 16;
  half8 h0, h1;
#pragma unroll
  for (int j = 0; j < 8; ++j) { h0[j] = T[kc + j][d]; h1[j] = T[kc + 8 + j][d]; }
  half8* dst = reinterpret_cast<half8*>(vt + gbase + (size_t)d * 2048 + kt * 64 + kc);
  dst[0] = h0;
  dst[1] = h1;
}

// ---------------------------------------------------------------------------
// m97-style GEMM: Out[M,N] = A[M,K] @ W[N,K]^T + bias (+resid)
// ---------------------------------------------------------------------------
template <bool WF32, bool RES>
__global__ __launch_bounds__(256) void gemm128(
    const _Float16* __restrict__ A, const void* __restrict__ Wp,
    const float* __restrict__ bias, const float* __restrict__ resid,
    void* __restrict__ Out, int N, float scale)
{
  constexpr int K = 1024;
  __shared__ _Float16 As[128 * 64];
  __shared__ _Float16 Bs[128 * 64];
  const int tid = threadIdx.x;
  const int lane = tid & 63, w = tid >> 6;
  const int lo = lane & 15, hi = lane >> 4;
  const int wr = w >> 1, wc = w & 1;
  const int rbase = blockIdx.x * 128, cbase = blockIdx.y * 128;
  const int e0 = w * 512 + lane * 8;

  f32x4 acc[4][4];
#pragma unroll
  for (int m = 0; m < 4; ++m)
#pragma unroll
    for (int n = 0; n < 4; ++n) acc[m][n] = f32x4{0.f, 0.f, 0.f, 0.f};

  for (int kk = 0; kk < K; kk += 64) {
    __syncthreads();
#pragma unroll
    for (int i = 0; i < 4; ++i) {
      const int e = i * 2048 + e0;
      gload_lds16(A + (size_t)(rbase + (e >> 6)) * K + kk + (e & 63),
                  (char*)As + i * 4096 + w * 1024);
    }
    if constexpr (!WF32) {
#pragma unroll
      for (int i = 0; i < 4; ++i) {
        const int e = i * 2048 + e0;
        gload_lds16((const _Float16*)Wp + (size_t)(cbase + (e >> 6)) * K + kk + (e & 63),
                    (char*)Bs + i * 4096 + w * 1024);
      }
    } else {
#pragma unroll
      for (int i = 0; i < 4; ++i) {
        const int e = i * 2048 + e0;
        const float4* src = reinterpret_cast<const float4*>(
            (const float*)Wp + (size_t)(cbase + (e >> 6)) * K + kk + (e & 63));
        const float4 f0 = src[0], f1 = src[1];
        half8 h;
        h[0] = (_Float16)f0.x; h[1] = (_Float16)f0.y; h[2] = (_Float16)f0.z; h[3] = (_Float16)f0.w;
        h[4] = (_Float16)f1.x; h[5] = (_Float16)f1.y; h[6] = (_Float16)f1.z; h[7] = (_Float16)f1.w;
        *reinterpret_cast<half8*>(Bs + e) = h;
      }
    }
    __syncthreads();
#pragma unroll
    for (int k0 = 0; k0 < 2; ++k0) {
      half8 a[4], b[4];
#pragma unroll
      for (int m = 0; m < 4; ++m)
        a[m] = *reinterpret_cast<const half8*>(As + (wr * 64 + m * 16 + lo) * 64 + k0 * 32 + hi * 8);
#pragma unroll
      for (int n = 0; n < 4; ++n)
        b[n] = *reinterpret_cast<const half8*>(Bs + (wc * 64 + n * 16 + lo) * 64 + k0 * 32 + hi * 8);
#pragma unroll
      for (int m = 0; m < 4; ++m)
#pragma unroll
        for (int n = 0; n < 4; ++n) acc[m][n] = MFMA16(a[m], b[n], acc[m][n]);
    }
  }
#pragma unroll
  for (int m = 0; m < 4; ++m) {
#pragma unroll
    for (int n = 0; n < 4; ++n) {
      const int col = cbase + wc * 64 + n * 16 + lo;
      const float bv = bias[col];
#pragma unroll
      for (int r = 0; r < 4; ++r) {
        const int row = rbase + wr * 64 + m * 16 + hi * 4 + r;
        float v = acc[m][n][r] + bv;
        if constexpr (RES) {
          v += resid[(size_t)row * 1024 + col];
          ((float*)Out)[(size_t)row * N + col] = v;
        } else {
          ((_Float16*)Out)[(size_t)row * N + col] = (_Float16)(v * scale);
        }
      }
    }
  }
}

// ---------------------------------------------------------------------------
// Fused attention, swapped-operand form, QBLK=256 / 8 waves, KBLK=128.
// KBLK=128 doubles the per-row attnp store burst to 512B (DRAM-page
// efficiency — R12 analysis: store stream capped at 4.5 TB/s with 256B
// row chunks). LDS = 128 KB (Kt 2x16K + Vt 2x16K + Ps 64K) -> 1 block/CU,
// 8 waves. grid 512 1-D: g = bid&63 -> per-group XCD affinity.
// Swapped QK^T: lane holds S[q-row = lo (+m*16+w*32)][k = nb*16+hi*4+r],
// nb=0..7. -dr in accumulator; cvt_pk pairs feed PV 16x16x16 MFMAs;
// wave-private swizzled Ps formats full-line nontemporal f32x4 stores.
// vmcnt(16) barrier: drains the 4 prefetch gloads (older), leaves this
// tile's 16 stores in flight.
// ---------------------------------------------------------------------------
__global__ __launch_bounds__(512) void attn_fused(
    const _Float16* __restrict__ qg, const _Float16* __restrict__ kg,
    const _Float16* __restrict__ vtg, _Float16* __restrict__ ctx,
    float* __restrict__ attnp)
{
  __shared__ _Float16 Kt[2][128 * 64];
  __shared__ _Float16 Vt[2][64 * 128];
  __shared__ float Ps[8 * 2048];  // per-wave 16 rows x 128 f32
  const int tid = threadIdx.x;
  const int lane = tid & 63, w = tid >> 6;
  const int lo = lane & 15, hi = lane >> 4;
  const int bid = blockIdx.x;
  const int g = bid & 63;
  const int q0 = (bid >> 6) * 256;
  const size_t gbase = (size_t)g * (2048 * 64);

  // K staging coords (tile 128x64 f16 = 16KB; 2 gloads/thread)
  const int eK0 = tid * 8, eK1 = 4096 + tid * 8;
  const int kr0 = eK0 >> 6, kc0 = (eK0 & 63) ^ ((kr0 & 7) << 3);
  const int kr1 = eK1 >> 6, kc1 = (eK1 & 63) ^ ((kr1 & 7) << 3);
  // V^T staging coords (tile 64x128 f16 = 16KB; 2 gloads/thread)
  const int vr0 = eK0 >> 7, vc0 = (eK0 & 127) ^ ((vr0 & 7) << 3);
  const int vr1 = eK1 >> 7, vc1 = (eK1 & 127) ^ ((vr1 & 7) << 3);

  float* ab = attnp + (size_t)g * 2048 * 2048;
  const _Float16* vtb = vtg + (size_t)g * (64 * 2048);
  float* Pw = Ps + w * 2048;

  // Q fragments (registers, both passes); q-row = q0 + w*32 + m*16 + lo.
  half8 qf[2][2];
#pragma unroll
  for (int m = 0; m < 2; ++m)
#pragma unroll
    for (int k0 = 0; k0 < 2; ++k0)
      qf[m][k0] = *reinterpret_cast<const half8*>(
          qg + gbase + (size_t)(q0 + w * 32 + m * 16 + lo) * 64 + k0 * 32 + hi * 8);

  float ls[2] = {0.f, 0.f};

  // ---------------- pass 1: denominators (16 K-tiles of 128) ------------
  gload_lds16(kg + gbase + (size_t)kr0 * 64 + kc0, (char*)Kt[0] + w * 1024);
  gload_lds16(kg + gbase + (size_t)kr1 * 64 + kc1, (char*)Kt[0] + 8192 + w * 1024);

  for (int kt = 0; kt < 16; ++kt) {
    const int cur = kt & 1;
    __syncthreads();
    if (kt < 15) {
      const _Float16* kn = kg + gbase + (size_t)(kt + 1) * (128 * 64);
      gload_lds16(kn + (size_t)kr0 * 64 + kc0, (char*)Kt[cur ^ 1] + w * 1024);
      gload_lds16(kn + (size_t)kr1 * 64 + kc1, (char*)Kt[cur ^ 1] + 8192 + w * 1024);
    }
    f32x4 s[2][8];
#pragma unroll
    for (int m = 0; m < 2; ++m)
#pragma unroll
      for (int n = 0; n < 8; ++n) s[m][n] = f32x4{0.f, 0.f, 0.f, 0.f};
#pragma unroll
    for (int k0 = 0; k0 < 2; ++k0) {
      half8 b[8];
#pragma unroll
      for (int n = 0; n < 8; ++n) {
        const int row = n * 16 + lo;
        b[n] = *reinterpret_cast<const half8*>(
            Kt[cur] + row * 64 + ((k0 * 32 + hi * 8) ^ ((row & 7) << 3)));
      }
#pragma unroll
      for (int m = 0; m < 2; ++m)
#pragma unroll
        for (int n = 0; n < 8; ++n) s[m][n] = MFMA16(b[n], qf[m][k0], s[m][n]);
    }
#pragma unroll
    for (int m = 0; m < 2; ++m) {
      float t = 0.f;
#pragma unroll
      for (int nb = 0; nb < 8; ++nb)
#pragma unroll
        for (int r = 0; r < 4; ++r) t += fexp2(s[m][nb][r]);
      ls[m] += t;
    }
  }

  float dr[2];
#pragma unroll
  for (int m = 0; m < 2; ++m) {
    float t = ls[m];
    t += __shfl_xor(t, 16, 64);
    t += __shfl_xor(t, 32, 64);
    dr[m] = __log2f(t);
  }

  f32x4 o[2][4];
#pragma unroll
  for (int m = 0; m < 2; ++m)
#pragma unroll
    for (int n = 0; n < 4; ++n) o[m][n] = f32x4{0.f, 0.f, 0.f, 0.f};

  // ---------------- pass 2: P stream + PV ----------------
  gload_lds16(kg + gbase + (size_t)kr0 * 64 + kc0, (char*)Kt[0] + w * 1024);
  gload_lds16(kg + gbase + (size_t)kr1 * 64 + kc1, (char*)Kt[0] + 8192 + w * 1024);
  gload_lds16(vtb + (size_t)vr0 * 2048 + vc0, (char*)Vt[0] + w * 1024);
  gload_lds16(vtb + (size_t)vr1 * 2048 + vc1, (char*)Vt[0] + 8192 + w * 1024);

  for (int kt = 0; kt < 16; ++kt) {
    const int cur = kt & 1;
    // drain the 4 older prefetch gloads; leave this tile's 16 stores in flight
    if (kt == 0) asm volatile("s_waitcnt vmcnt(0) lgkmcnt(0)" ::: "memory");
    else asm volatile("s_waitcnt vmcnt(16) lgkmcnt(0)" ::: "memory");
    __builtin_amdgcn_s_barrier();
    __builtin_amdgcn_sched_barrier(0);
    if (kt < 15) {
      const _Float16* kn = kg + gbase + (size_t)(kt + 1) * (128 * 64);
      const _Float16* vn = vtb + (kt + 1) * 128;
      gload_lds16(kn + (size_t)kr0 * 64 + kc0, (char*)Kt[cur ^ 1] + w * 1024);
      gload_lds16(kn + (size_t)kr1 * 64 + kc1, (char*)Kt[cur ^ 1] + 8192 + w * 1024);
      gload_lds16(vn + (size_t)vr0 * 2048 + vc0, (char*)Vt[cur ^ 1] + w * 1024);
      gload_lds16(vn + (size_t)vr1 * 2048 + vc1, (char*)Vt[cur ^ 1] + 8192 + w * 1024);
    }
    __builtin_amdgcn_sched_barrier(0);
    // QK^T (swapped), accumulator pre-loaded with -dr
    f32x4 s[2][8];
#pragma unroll
    for (int m = 0; m < 2; ++m)
#pragma unroll
      for (int n = 0; n < 8; ++n) s[m][n] = f32x4{-dr[m], -dr[m], -dr[m], -dr[m]};
#pragma unroll
    for (int k0 = 0; k0 < 2; ++k0) {
      half8 b[8];
#pragma unroll
      for (int n = 0; n < 8; ++n) {
        const int row = n * 16 + lo;
        b[n] = *reinterpret_cast<const half8*>(
            Kt[cur] + row * 64 + ((k0 * 32 + hi * 8) ^ ((row & 7) << 3)));
      }
#pragma unroll
      for (int m = 0; m < 2; ++m)
#pragma unroll
        for (int n = 0; n < 8; ++n) s[m][n] = MFMA16(b[n], qf[m][k0], s[m][n]);
    }
    // per m: exp -> pk + Ps format -> full-line nt stores (512B/row) -> PV
#pragma unroll
    for (int m = 0; m < 2; ++m) {
      int pk[8][2];
#pragma unroll
      for (int nb = 0; nb < 8; ++nb) {
        const float p0 = fexp2(s[m][nb][0]);
        const float p1 = fexp2(s[m][nb][1]);
        const float p2 = fexp2(s[m][nb][2]);
        const float p3 = fexp2(s[m][nb][3]);
        pk[nb][0] = cvtpk16(p0, p1);
        pk[nb][1] = cvtpk16(p2, p3);
        const f32x4 f = {p0, p1, p2, p3};
        *reinterpret_cast<f32x4*>(
            Pw + lo * 128 + ((nb * 16 + hi * 4) ^ ((lo & 7) << 2))) = f;
      }
      asm volatile("s_waitcnt lgkmcnt(0)" ::: "memory");
#pragma unroll
      for (int i = 0; i < 8; ++i) {
        const int rl = i * 2 + (lane >> 5);      // local row 0..15
        const int klo = (lane & 31) * 4;         // col 0..124
        const f32x4 f = *reinterpret_cast<const f32x4*>(
            Pw + rl * 128 + (klo ^ ((rl & 7) << 2)));
        __builtin_nontemporal_store(
            f, reinterpret_cast<f32x4*>(
                   ab + (size_t)(q0 + w * 32 + m * 16 + rl) * 2048 + kt * 128 + klo));
      }
      asm volatile("s_waitcnt lgkmcnt(0)" ::: "memory");  // WAR before next m
      // PV for this m
#pragma unroll
      for (int nb = 0; nb < 8; ++nb) {
        half4 vb[4];
#pragma unroll
        for (int n = 0; n < 4; ++n) {
          const int d = n * 16 + lo;
          vb[n] = *reinterpret_cast<const half4*>(
              Vt[cur] + d * 128 + ((nb * 16 + hi * 4) ^ ((d & 7) << 3)));
        }
        const int2v t2 = {pk[nb][0], pk[nb][1]};
        const half4 pa = __builtin_bit_cast(half4, t2);
#pragma unroll
        for (int n = 0; n < 4; ++n) o[m][n] = MFMA16x16(pa, vb[n], o[m][n]);
      }
    }
  }
#pragma unroll
  for (int m = 0; m < 2; ++m)
#pragma unroll
    for (int n = 0; n < 4; ++n)
#pragma unroll
      for (int r = 0; r < 4; ++r)
        ctx[gbase + (size_t)(q0 + w * 32 + m * 16 + hi * 4 + r) * 64 + n * 16 + lo] =
            (_Float16)o[m][n][r];
}

// ---------------------------------------------------------------------------
// In-place LayerNorm over rows of x[8192][1024]
// ---------------------------------------------------------------------------
__global__ __launch_bounds__(256) void ln_kernel(
    float* __restrict__ x, const float* __restrict__ gamma, const float* __restrict__ beta)
{
  const int row = blockIdx.x;
  const int t = threadIdx.x;
  float4 v = *reinterpret_cast<float4*>(x + (size_t)row * 1024 + t * 4);
  float s = v.x + v.y + v.z + v.w;
  float ss = v.x * v.x + v.y * v.y + v.z * v.z + v.w * v.w;
#pragma unroll
  for (int off = 1; off < 64; off <<= 1) {
    s += __shfl_xor(s, off, 64);
    ss += __shfl_xor(ss, off, 64);
  }
  __shared__ float sm[8];
  const int wv = t >> 6, ln = t & 63;
  if (ln == 0) { sm[wv] = s; sm[4 + wv] = ss; }
  __syncthreads();
  s = sm[0] + sm[1] + sm[2] + sm[3];
  ss = sm[4] + sm[5] + sm[6] + sm[7];
  const float mu = s * (1.0f / 1024.0f);
  const float var = ss * (1.0f / 1024.0f) - mu * mu;
  const float rstd = rsqrtf(var + 1e-5f);
  const float4 gv = *reinterpret_cast<const float4*>(gamma + t * 4);
  const float4 bv = *reinterpret_cast<const float4*>(beta + t * 4);
  v.x = (v.x - mu) * rstd * gv.x + bv.x;
  v.y = (v.y - mu) * rstd * gv.y + bv.y;
  v.z = (v.z - mu) * rstd * gv.z + bv.z;
  v.w = (v.w - mu) * rstd * gv.w + bv.w;
  *reinterpret_cast<float4*>(x + (size_t)row * 1024 + t * 4) = v;
}

// ---------------------------------------------------------------------------
extern "C" void kernel_launch(void* const* d_in, const int* in_sizes, int n_in,
                              void* d_out, int out_size, void* d_ws, size_t ws_size,
                              hipStream_t stream) {
  const float* query = (const float*)d_in[0];
  const float* key_ = (const float*)d_in[1];
  const float* value = (const float*)d_in[2];
  const float* Wq = (const float*)d_in[3];
  const float* bq = (const float*)d_in[4];
  const float* Wk = (const float*)d_in[5];
  const float* bk = (const float*)d_in[6];
  const float* Wv = (const float*)d_in[7];
  const float* bv = (const float*)d_in[8];
  const float* Wo = (const float*)d_in[9];
  const float* bo = (const float*)d_in[10];
  const float* gamma = (const float*)d_in[11];
  const float* beta = (const float*)d_in[12];

  float* out = (float*)d_out;
  float* attnp = out + (size_t)8192 * 1024;

  // f16 conversion scratch in the not-yet-written attention output region.
  _Float16* xq = (_Float16*)attnp;
  _Float16* xk = xq + (size_t)8388608;
  _Float16* xv = xk + (size_t)8388608;
  _Float16* wq16 = xv + (size_t)8388608;
  _Float16* wk16 = wq16 + (size_t)1048576;
  _Float16* wv16 = wk16 + (size_t)1048576;

  // vt (16.8 MB) in out[0:16.8MB] — dead until out-proj.
  _Float16* vt = (_Float16*)out;

  _Float16* qb = (_Float16*)d_ws;
  _Float16* kb2 = qb + (size_t)8388608;
  _Float16* vb2 = kb2 + (size_t)8388608;
  _Float16* ctx = vb2;  // vb2 free after vtrans

  constexpr float QSCALE = 0.125f * 1.44269504088896f;

  cvt_f16<<<dim3(13824), dim3(256), 0, stream>>>(query, key_, value, Wq, Wk, Wv,
                                                 xq, xk, xv, wq16, wk16, wv16);
  gemm128<false, false><<<dim3(64, 8), dim3(256), 0, stream>>>(xq, wq16, bq, nullptr, qb, 1024, QSCALE);
  gemm128<false, false><<<dim3(64, 8), dim3(256), 0, stream>>>(xk, wk16, bk, nullptr, kb2, 1024, 1.0f);
  gemm128<false, false><<<dim3(64, 8), dim3(256), 0, stream>>>(xv, wv16, bv, nullptr, vb2, 1024, 1.0f);
  vtrans<<<dim3(32, 64), dim3(256), 0, stream>>>(vb2, vt);
  attn_fused<<<dim3(512), dim3(512), 0, stream>>>(qb, kb2, vt, ctx, attnp);
  gemm128<true, true><<<dim3(64, 8), dim3(256), 0, stream>>>(ctx, Wo, bo, query, out, 1024, 1.0f);
  ln_kernel<<<dim3(8192), dim3(256), 0, stream>>>(out, gamma, beta);
}